// Round 9
// baseline (113.799 us; speedup 1.0000x reference)
//
#include <hip/hip_runtime.h>
#include <hip/hip_bf16.h>

// Problem constants (inputs fp32, confirmed round 3)
#define NB 16      // batches
#define NC 64      // channels
#define NN 4096    // H*W query length
#define NM 1024    // pooled kv length
#define ND 8       // C/HEADS attention dim
#define NG 32      // C/2 g channels

typedef short short8 __attribute__((ext_vector_type(8)));
typedef float floatx4 __attribute__((ext_vector_type(4)));

#define LOG2E 1.44269504f

__device__ __forceinline__ short f2bfs(float f) {
    union { __hip_bfloat16 h; short s; } u;
    u.h = __float2bfloat16(f);
    return u.s;
}
__device__ __forceinline__ unsigned pack2bf(float a, float b) {   // accurate RNE (proj)
    return (unsigned)(unsigned short)f2bfs(a) | ((unsigned)(unsigned short)f2bfs(b) << 16);
}
__device__ __forceinline__ unsigned pk2fast(float a, float b) {   // round-half-up, 3 instrs
    unsigned ua = __float_as_uint(a) + 0x8000u;
    unsigned ub = __float_as_uint(b) + 0x8000u;
    return __builtin_amdgcn_perm(ub, ua, 0x07060302);
}
__device__ __forceinline__ short8 u4s8(uint4 v) {
    union { uint4 u; short8 s; } c; c.u = v; return c.s;
}

// ---------------------------------------------------------------------------
// Kernel 1: projections (unchanged from round 8).
//   theta_ws [b][4096][8] bf16, pre-scaled by log2(e)               (1 MB)
//   phi_ws   [b][1024][8] bf16                                      (256 KB)
//   g2_ws    g2 = w_o@g in PV A-frag order:
//            uint4[b][ct(4)][kg(32)][lane(64)]; lane(quad,lm):
//            .xy = g2[ct*16+lm][kg*32 +    quad*4 + 0..3]   (kt0)
//            .zw = g2[ct*16+lm][kg*32 + 16 + quad*4 + 0..3] (kt1)
// grid = NB*32 blocks (b, row-pair ph = kg), 256 threads.
// ---------------------------------------------------------------------------
__global__ __launch_bounds__(256)
void proj_kernel(const float* __restrict__ x,
                 const float* __restrict__ w_theta,
                 const float* __restrict__ w_phi,
                 const float* __restrict__ w_g,
                 const float* __restrict__ w_o,
                 unsigned* __restrict__ theta_ws,
                 unsigned* __restrict__ phi_ws,
                 unsigned* __restrict__ g2_ws)
{
    __shared__ __align__(16) float xl[64 * 128];  // [c][pos] 32 KB
    __shared__ float lwt[512];                    // theta W, [oc][c] (uniform reads)
    __shared__ float lwp[512];                    // phi   W, [oc][c]
    __shared__ __align__(8) float lwgT[64 * 34];  // g W transposed [c][oc], pad 34
    __shared__ float lwoT[32 * 65];               // o W transposed [c][co], pad 65
    __shared__ __align__(16) float lgs[32 * 36];  // g pooled [c][m], pad 36
    __shared__ float lps[32 * 8];                 // phi pooled [m][oc]

    const int b  = blockIdx.x >> 5;
    const int ph = blockIdx.x & 31;
    const int t  = threadIdx.x;

    for (int i = t; i < 512;  i += 256) { lwt[i] = w_theta[i]; lwp[i] = w_phi[i]; }
    for (int i = t; i < 2048; i += 256) {
        lwgT[(i & 63) * 34 + (i >> 6)] = w_g[i];   // w_g flat [oc][c] -> [c][oc]
        lwoT[(i & 31) * 65 + (i >> 5)] = w_o[i];   // w_o flat [co][c] -> [c][co]
    }

    const float* xb = x + (size_t)b * NC * NN + (size_t)ph * 128;
    for (int idx = t; idx < 2048; idx += 256) {
        int c = idx >> 5, i4 = idx & 31;
        ((float4*)xl)[c * 32 + i4] = ((const float4*)(xb + (size_t)c * NN))[i4];
    }
    __syncthreads();

    if (t < 128) {
        // ---- theta: position ph*128+t, 8 oc, pre-scaled by log2e
        float th[8];
        #pragma unroll
        for (int oc = 0; oc < 8; ++oc) th[oc] = 0.f;
        for (int c = 0; c < 64; ++c) {
            float xv = xl[c * 128 + t];
            #pragma unroll
            for (int oc = 0; oc < 8; ++oc) th[oc] = fmaf(lwt[oc * 64 + c], xv, th[oc]);
        }
        uint4 pk;
        pk.x = pack2bf(th[0] * LOG2E, th[1] * LOG2E);
        pk.y = pack2bf(th[2] * LOG2E, th[3] * LOG2E);
        pk.z = pack2bf(th[4] * LOG2E, th[5] * LOG2E);
        pk.w = pack2bf(th[6] * LOG2E, th[7] * LOG2E);
        ((uint4*)theta_ws)[(size_t)b * NN + ph * 128 + t] = pk;

        // ---- phi pooled: m = t>>2, oc pair = (t&3)*2
        int m = t >> 2, oc0 = (t & 3) * 2;
        float s[2][4];
        #pragma unroll
        for (int a = 0; a < 2; ++a)
            #pragma unroll
            for (int p = 0; p < 4; ++p) s[a][p] = 0.f;
        #pragma unroll 4
        for (int c = 0; c < 64; ++c) {
            const float* xr = &xl[c * 128];
            float x0 = xr[2 * m], x1 = xr[2 * m + 1], x2 = xr[64 + 2 * m], x3 = xr[65 + 2 * m];
            #pragma unroll
            for (int a = 0; a < 2; ++a) {
                float w = lwp[(oc0 + a) * 64 + c];
                s[a][0] = fmaf(w, x0, s[a][0]);
                s[a][1] = fmaf(w, x1, s[a][1]);
                s[a][2] = fmaf(w, x2, s[a][2]);
                s[a][3] = fmaf(w, x3, s[a][3]);
            }
        }
        #pragma unroll
        for (int a = 0; a < 2; ++a)
            lps[m * 8 + oc0 + a] = fmaxf(fmaxf(s[a][0], s[a][1]), fmaxf(s[a][2], s[a][3]));
    } else {
        // ---- g conv: tt in [0,128): oc pair = 2*(tt>>3), position group grp = tt&7
        int tt = t - 128;
        int oc0 = (tt >> 3) * 2, grp = tt & 7;
        float s0[16], s1[16];
        #pragma unroll
        for (int i = 0; i < 16; ++i) { s0[i] = 0.f; s1[i] = 0.f; }
        const float4* xl4 = (const float4*)xl;
        #pragma unroll 2
        for (int c = 0; c < 64; ++c) {
            float4 a0 = xl4[c * 32 + 2 * grp];
            float4 a1 = xl4[c * 32 + 2 * grp + 1];
            float4 b0 = xl4[c * 32 + 16 + 2 * grp];
            float4 b1 = xl4[c * 32 + 17 + 2 * grp];
            float2 wv = *(const float2*)&lwgT[c * 34 + oc0];   // broadcast, conflict-free
            float w0 = wv.x, w1 = wv.y;
            s0[0] = fmaf(w0, a0.x, s0[0]);  s0[1] = fmaf(w0, a0.y, s0[1]);
            s0[2] = fmaf(w0, a0.z, s0[2]);  s0[3] = fmaf(w0, a0.w, s0[3]);
            s0[4] = fmaf(w0, a1.x, s0[4]);  s0[5] = fmaf(w0, a1.y, s0[5]);
            s0[6] = fmaf(w0, a1.z, s0[6]);  s0[7] = fmaf(w0, a1.w, s0[7]);
            s0[8] = fmaf(w0, b0.x, s0[8]);  s0[9] = fmaf(w0, b0.y, s0[9]);
            s0[10] = fmaf(w0, b0.z, s0[10]); s0[11] = fmaf(w0, b0.w, s0[11]);
            s0[12] = fmaf(w0, b1.x, s0[12]); s0[13] = fmaf(w0, b1.y, s0[13]);
            s0[14] = fmaf(w0, b1.z, s0[14]); s0[15] = fmaf(w0, b1.w, s0[15]);
            s1[0] = fmaf(w1, a0.x, s1[0]);  s1[1] = fmaf(w1, a0.y, s1[1]);
            s1[2] = fmaf(w1, a0.z, s1[2]);  s1[3] = fmaf(w1, a0.w, s1[3]);
            s1[4] = fmaf(w1, a1.x, s1[4]);  s1[5] = fmaf(w1, a1.y, s1[5]);
            s1[6] = fmaf(w1, a1.z, s1[6]);  s1[7] = fmaf(w1, a1.w, s1[7]);
            s1[8] = fmaf(w1, b0.x, s1[8]);  s1[9] = fmaf(w1, b0.y, s1[9]);
            s1[10] = fmaf(w1, b0.z, s1[10]); s1[11] = fmaf(w1, b0.w, s1[11]);
            s1[12] = fmaf(w1, b1.x, s1[12]); s1[13] = fmaf(w1, b1.y, s1[13]);
            s1[14] = fmaf(w1, b1.z, s1[14]); s1[15] = fmaf(w1, b1.w, s1[15]);
        }
        #pragma unroll
        for (int p = 0; p < 4; ++p) {
            float v0 = fmaxf(fmaxf(s0[2 * p], s0[2 * p + 1]), fmaxf(s0[8 + 2 * p], s0[9 + 2 * p]));
            float v1 = fmaxf(fmaxf(s1[2 * p], s1[2 * p + 1]), fmaxf(s1[8 + 2 * p], s1[9 + 2 * p]));
            lgs[oc0 * 36 + grp * 4 + p]       = v0;
            lgs[(oc0 + 1) * 36 + grp * 4 + p] = v1;
        }
    }
    __syncthreads();

    // ---- g2 = w_o @ g, written in PV A-frag order
    {
        int co = t >> 2, sel = t & 3;      // sel = quad
        int m0a = 4 * sel, m0b = 16 + 4 * sel;
        float v[8];
        #pragma unroll
        for (int mm = 0; mm < 8; ++mm) v[mm] = 0.f;
        #pragma unroll 4
        for (int c = 0; c < 32; ++c) {
            float w = lwoT[c * 65 + co];   // transposed: 2 lanes/bank, conflict-free
            float4 ga = *(const float4*)&lgs[c * 36 + m0a];
            float4 gb = *(const float4*)&lgs[c * 36 + m0b];
            v[0] = fmaf(w, ga.x, v[0]); v[1] = fmaf(w, ga.y, v[1]);
            v[2] = fmaf(w, ga.z, v[2]); v[3] = fmaf(w, ga.w, v[3]);
            v[4] = fmaf(w, gb.x, v[4]); v[5] = fmaf(w, gb.y, v[5]);
            v[6] = fmaf(w, gb.z, v[6]); v[7] = fmaf(w, gb.w, v[7]);
        }
        uint4 pk;
        pk.x = pack2bf(v[0], v[1]); pk.y = pack2bf(v[2], v[3]);   // kt0 keys 4sel..+3
        pk.z = pack2bf(v[4], v[5]); pk.w = pack2bf(v[6], v[7]);   // kt1 keys 16+4sel..+3
        int lane = (sel << 4) | (co & 15);
        ((uint4*)g2_ws)[(((size_t)b * 4 + (co >> 4)) * 32 + ph) * 64 + lane] = pk;
    }

    // ---- phi pack
    if (t < 32) {
        const float* pr = &lps[t * 8];
        uint4 pk;
        pk.x = pack2bf(pr[0], pr[1]); pk.y = pack2bf(pr[2], pr[3]);
        pk.z = pack2bf(pr[4], pr[5]); pk.w = pack2bf(pr[6], pr[7]);
        ((uint4*)phi_ws)[(size_t)b * NM + ph * 32 + t] = pk;
    }
}

// ---------------------------------------------------------------------------
// Kernel 2: flash attention, S and PV on mfma_f32_16x16x32_bf16.
// Round-9: (a) kt0+kt1 fused in ONE PV mfma: B slots j0-3 = kt0 evals,
// j4-7 = kt1 evals -- matches g2 A-frag (.xy=kt0 keys, .zw=kt1 keys), so
// PV mfma count halves and the a1 shuffle disappears. (b) 16 q per wave,
// grid NB*64 = 1024 blocks, __launch_bounds__(256,4) -> 4 blocks/CU
// (4 waves/SIMD): 2x latency hiding for the S->exp->pack->PV chain.
// ---------------------------------------------------------------------------
__global__ __launch_bounds__(256, 4)
void attn_kernel(const unsigned* __restrict__ theta_ws,
                 const unsigned* __restrict__ phi_ws,
                 const unsigned* __restrict__ g2_ws,
                 const float* __restrict__ gamma_p,
                 const float* __restrict__ x,
                 float* __restrict__ out)
{
    // 17408 B: phi frags (16 KB) during main loop, [64][68] transpose after
    __shared__ __align__(16) float smem_f[64 * 68];
    uint4* lphi = (uint4*)smem_f;
    float* ltr  = smem_f;

    const int b    = blockIdx.x >> 6;
    const int qblk = blockIdx.x & 63;
    const int t    = threadIdx.x;
    const int w    = t >> 6;
    const int lane = t & 63;
    const int lm   = lane & 15;
    const int quad = lane >> 4;
    const int q0   = qblk * 64 + w * 16;

    // stage phi (raw bf16 frag copy)
    for (int kk = t; kk < NM; kk += 256)
        lphi[kk] = ((const uint4*)phi_ws)[(size_t)b * NM + kk];

    // theta B-frag (loop-invariant): quad0 holds theta[q][d0..7], rest zero
    uint4 tb;
    {
        uint4 v = ((const uint4*)theta_ws)[(size_t)b * NN + q0 + lm];
        tb.x = quad == 0 ? v.x : 0u;
        tb.y = quad == 0 ? v.y : 0u;
        tb.z = quad == 0 ? v.z : 0u;
        tb.w = quad == 0 ? v.w : 0u;
    }

    floatx4 acc[4];
    #pragma unroll
    for (int ct = 0; ct < 4; ++ct) acc[ct] = (floatx4)0.f;
    float lsum = 0.f;

    const uint4* gf = (const uint4*)g2_ws;
    uint4 ga[4], gn[4];
    #pragma unroll
    for (int ct = 0; ct < 4; ++ct)
        ga[ct] = gf[(((size_t)b * 4 + ct) * 32 + 0) * 64 + lane];

    __syncthreads();

    uint4 pp0 = lphi[lm];        // phi A-frags for kg=0 (keys 0-15 / 16-31)
    uint4 pp1 = lphi[16 + lm];

    for (int kg = 0; kg < 32; ++kg) {
        uint4 pn0, pn1;
        if (kg + 1 < 32) {                       // prefetch next kg
            pn0 = lphi[(kg + 1) * 32 + lm];
            pn1 = lphi[(kg + 1) * 32 + 16 + lm];
            #pragma unroll
            for (int ct = 0; ct < 4; ++ct)
                gn[ct] = gf[(((size_t)b * 4 + ct) * 32 + kg + 1) * 64 + lane];
        }

        // S: D[k16 = quad*4+r][q = lm]
        floatx4 s0 = __builtin_amdgcn_mfma_f32_16x16x32_bf16(
            u4s8(pp0), u4s8(tb), (floatx4)0.f, 0, 0, 0);
        floatx4 s1 = __builtin_amdgcn_mfma_f32_16x16x32_bf16(
            u4s8(pp1), u4s8(tb), (floatx4)0.f, 0, 0, 0);
        float e0[4], e1[4];
        #pragma unroll
        for (int r = 0; r < 4; ++r) {
            e0[r] = __builtin_amdgcn_exp2f(s0[r]);   // theta pre-scaled by log2e
            e1[r] = __builtin_amdgcn_exp2f(s1[r]);
        }
        lsum += ((e0[0] + e0[1]) + (e0[2] + e0[3]))
              + ((e1[0] + e1[1]) + (e1[2] + e1[3]));
        // B-frag: slots j0-3 = kt0 evals, j4-7 = kt1 evals (matches ga layout)
        uint4 pb = make_uint4(pk2fast(e0[0], e0[1]), pk2fast(e0[2], e0[3]),
                              pk2fast(e1[0], e1[1]), pk2fast(e1[2], e1[3]));
        #pragma unroll
        for (int ct = 0; ct < 4; ++ct)
            acc[ct] = __builtin_amdgcn_mfma_f32_16x16x32_bf16(
                u4s8(ga[ct]), u4s8(pb), acc[ct], 0, 0, 0);

        #pragma unroll
        for (int ct = 0; ct < 4; ++ct) ga[ct] = gn[ct];
        pp0 = pn0; pp1 = pn1;
    }

    // softmax denominator: lane holds keys {quad*4+r} u {16+quad*4+r} per kg
    // at q=lm; quads partition all keys -> reduce across quads.
    float inv;
    {
        float l = lsum;
        l += __shfl_xor(l, 16);
        l += __shfl_xor(l, 32);
        inv = 1.0f / l;
    }

    const float gamma = gamma_p[0];

    // transpose epilogue: normalized acc -> ltr[co][q'], then coalesced I/O
    __syncthreads();   // all waves done with lphi
    #pragma unroll
    for (int ct = 0; ct < 4; ++ct)
        #pragma unroll
        for (int r = 0; r < 4; ++r)
            ltr[(ct * 16 + quad * 4 + r) * 68 + w * 16 + lm] = acc[ct][r] * inv;
    __syncthreads();

    // thread: co = t>>2, q-segment (t&3)*16 .. +16 (4 float4 each)
    {
        const int co = t >> 2, seg = (t & 3) * 16;
        size_t base = ((size_t)b * NC + co) * NN + qblk * 64 + seg;
        const float* tr = &ltr[co * 68 + seg];
        #pragma unroll
        for (int i = 0; i < 4; ++i) {
            float4 tv = ((const float4*)tr)[i];
            float4 xv = *(const float4*)(x + base + i * 4);
            float4 ov = make_float4(fmaf(gamma, tv.x, xv.x), fmaf(gamma, tv.y, xv.y),
                                    fmaf(gamma, tv.z, xv.z), fmaf(gamma, tv.w, xv.w));
            *(float4*)(out + base + i * 4) = ov;
        }
    }
}

// ---------------------------------------------------------------------------
extern "C" void kernel_launch(void* const* d_in, const int* in_sizes, int n_in,
                              void* d_out, int out_size, void* d_ws, size_t ws_size,
                              hipStream_t stream)
{
    const float* x  = (const float*)d_in[0];
    const float* wt = (const float*)d_in[1];
    const float* wp = (const float*)d_in[2];
    const float* wg = (const float*)d_in[3];
    const float* wo = (const float*)d_in[4];
    const float* gm = (const float*)d_in[5];
    float* out = (float*)d_out;

    // ws (bf16, packed): theta 1 MB | phi 256 KB | g2 (frag order) 2 MB
    unsigned* theta_ws = (unsigned*)d_ws;
    unsigned* phi_ws   = theta_ws + (size_t)NB * NN * ND / 2;
    unsigned* g2_ws    = phi_ws   + (size_t)NB * NM * ND / 2;

    proj_kernel<<<NB * 32, 256, 0, stream>>>(x, wt, wp, wg, wo, theta_ws, phi_ws, g2_ws);
    attn_kernel<<<NB * 64, 256, 0, stream>>>(theta_ws, phi_ws, g2_ws, gm, x, out);
}

// Round 10
// 113.202 us; speedup vs baseline: 1.0053x; 1.0053x over previous
//
#include <hip/hip_runtime.h>
#include <hip/hip_bf16.h>

// Problem constants (inputs fp32, confirmed round 3)
#define NB 16      // batches
#define NC 64      // channels
#define NN 4096    // H*W query length
#define NM 1024    // pooled kv length
#define ND 8       // C/HEADS attention dim
#define NG 32      // C/2 g channels

typedef short short8 __attribute__((ext_vector_type(8)));
typedef float floatx4 __attribute__((ext_vector_type(4)));

#define LOG2E 1.44269504f

__device__ __forceinline__ short f2bfs(float f) {
    union { __hip_bfloat16 h; short s; } u;
    u.h = __float2bfloat16(f);
    return u.s;
}
__device__ __forceinline__ unsigned pack2bf(float a, float b) {   // accurate RNE
    return (unsigned)(unsigned short)f2bfs(a) | ((unsigned)(unsigned short)f2bfs(b) << 16);
}
__device__ __forceinline__ unsigned pk2fast(float a, float b) {   // round-half-up, 3 instrs
    unsigned ua = __float_as_uint(a) + 0x8000u;
    unsigned ub = __float_as_uint(b) + 0x8000u;
    return __builtin_amdgcn_perm(ub, ua, 0x07060302);
}
__device__ __forceinline__ short8 u4s8(uint4 v) {
    union { uint4 u; short8 s; } c; c.u = v; return c.s;
}

// ---------------------------------------------------------------------------
// Kernel 1: phi + g projections (theta moved into attn — it is block-local).
//   phi_ws [b][1024][8] bf16                                      (256 KB)
//   g2_ws  g2 = w_o@g in PV A-frag order:
//          uint4[b][ct(4)][kg(32)][lane(64)]; lane(quad,lm):
//          .xy = g2[ct*16+lm][kg*32 +    quad*4 + 0..3]   (kt0)
//          .zw = g2[ct*16+lm][kg*32 + 16 + quad*4 + 0..3] (kt1)
// grid = NB*32 blocks (b, row-pair ph = kg), 256 threads.
// All weight tables transposed in LDS -> broadcast reads, no conflicts.
// ---------------------------------------------------------------------------
__global__ __launch_bounds__(256)
void proj_kernel(const float* __restrict__ x,
                 const float* __restrict__ w_phi,
                 const float* __restrict__ w_g,
                 const float* __restrict__ w_o,
                 unsigned* __restrict__ phi_ws,
                 unsigned* __restrict__ g2_ws)
{
    __shared__ __align__(16) float xl[64 * 128];  // [c][pos] 32 KB
    __shared__ float lwpT[64 * 8];                // phi W transposed [c][oc]
    __shared__ __align__(8) float lwgT[64 * 34];  // g W transposed [c][oc], pad 34
    __shared__ float lwoT[32 * 65];               // o W transposed [c][co], pad 65
    __shared__ __align__(16) float lgs[32 * 36];  // g pooled [c][m], pad 36
    __shared__ float lps[32 * 8];                 // phi pooled [m][oc]

    const int b  = blockIdx.x >> 5;
    const int ph = blockIdx.x & 31;
    const int t  = threadIdx.x;

    for (int i = t; i < 512; i += 256) lwpT[(i & 63) * 8 + (i >> 6)] = w_phi[i];
    for (int i = t; i < 2048; i += 256) {
        lwgT[(i & 63) * 34 + (i >> 6)] = w_g[i];   // [oc][c] -> [c][oc]
        lwoT[(i & 31) * 65 + (i >> 5)] = w_o[i];   // [co][c] -> [c][co]
    }

    const float* xb = x + (size_t)b * NC * NN + (size_t)ph * 128;
    for (int idx = t; idx < 2048; idx += 256) {
        int c = idx >> 5, i4 = idx & 31;
        ((float4*)xl)[c * 32 + i4] = ((const float4*)(xb + (size_t)c * NN))[i4];
    }
    __syncthreads();

    // ---- g conv + pool: 256 threads, oc = t>>3, position group grp = t&7
    {
        int oc = t >> 3, grp = t & 7;
        float s0[16];
        #pragma unroll
        for (int i = 0; i < 16; ++i) s0[i] = 0.f;
        const float4* xl4 = (const float4*)xl;
        #pragma unroll 4
        for (int c = 0; c < 64; ++c) {
            float4 a0 = xl4[c * 32 + 2 * grp];
            float4 a1 = xl4[c * 32 + 2 * grp + 1];
            float4 b0 = xl4[c * 32 + 16 + 2 * grp];
            float4 b1 = xl4[c * 32 + 17 + 2 * grp];
            float w0 = lwgT[c * 34 + oc];            // 8-way broadcast, conflict-free
            s0[0] = fmaf(w0, a0.x, s0[0]);  s0[1] = fmaf(w0, a0.y, s0[1]);
            s0[2] = fmaf(w0, a0.z, s0[2]);  s0[3] = fmaf(w0, a0.w, s0[3]);
            s0[4] = fmaf(w0, a1.x, s0[4]);  s0[5] = fmaf(w0, a1.y, s0[5]);
            s0[6] = fmaf(w0, a1.z, s0[6]);  s0[7] = fmaf(w0, a1.w, s0[7]);
            s0[8] = fmaf(w0, b0.x, s0[8]);  s0[9] = fmaf(w0, b0.y, s0[9]);
            s0[10] = fmaf(w0, b0.z, s0[10]); s0[11] = fmaf(w0, b0.w, s0[11]);
            s0[12] = fmaf(w0, b1.x, s0[12]); s0[13] = fmaf(w0, b1.y, s0[13]);
            s0[14] = fmaf(w0, b1.z, s0[14]); s0[15] = fmaf(w0, b1.w, s0[15]);
        }
        #pragma unroll
        for (int p = 0; p < 4; ++p)
            lgs[oc * 36 + grp * 4 + p] =
                fmaxf(fmaxf(s0[2 * p], s0[2 * p + 1]), fmaxf(s0[8 + 2 * p], s0[9 + 2 * p]));
    }

    // ---- phi conv + pool: 256 threads, m = t>>3, oc = t&7 (one output each)
    {
        int m = t >> 3, oc = t & 7;
        float s0 = 0.f, s1 = 0.f, s2 = 0.f, s3 = 0.f;
        #pragma unroll 4
        for (int c = 0; c < 64; ++c) {
            float w = lwpT[c * 8 + oc];              // 8-way broadcast
            const float* xr = &xl[c * 128];
            s0 = fmaf(w, xr[2 * m],      s0);
            s1 = fmaf(w, xr[2 * m + 1],  s1);
            s2 = fmaf(w, xr[64 + 2 * m], s2);
            s3 = fmaf(w, xr[65 + 2 * m], s3);
        }
        lps[m * 8 + oc] = fmaxf(fmaxf(s0, s1), fmaxf(s2, s3));
    }
    __syncthreads();

    // ---- g2 = w_o @ g, written in PV A-frag order
    {
        int co = t >> 2, sel = t & 3;      // sel = quad
        int m0a = 4 * sel, m0b = 16 + 4 * sel;
        float v[8];
        #pragma unroll
        for (int mm = 0; mm < 8; ++mm) v[mm] = 0.f;
        #pragma unroll 4
        for (int c = 0; c < 32; ++c) {
            float w = lwoT[c * 65 + co];
            float4 ga = *(const float4*)&lgs[c * 36 + m0a];
            float4 gb = *(const float4*)&lgs[c * 36 + m0b];
            v[0] = fmaf(w, ga.x, v[0]); v[1] = fmaf(w, ga.y, v[1]);
            v[2] = fmaf(w, ga.z, v[2]); v[3] = fmaf(w, ga.w, v[3]);
            v[4] = fmaf(w, gb.x, v[4]); v[5] = fmaf(w, gb.y, v[5]);
            v[6] = fmaf(w, gb.z, v[6]); v[7] = fmaf(w, gb.w, v[7]);
        }
        uint4 pk;
        pk.x = pack2bf(v[0], v[1]); pk.y = pack2bf(v[2], v[3]);   // kt0
        pk.z = pack2bf(v[4], v[5]); pk.w = pack2bf(v[6], v[7]);   // kt1
        int lane = (sel << 4) | (co & 15);
        ((uint4*)g2_ws)[(((size_t)b * 4 + (co >> 4)) * 32 + ph) * 64 + lane] = pk;
    }

    // ---- phi pack
    if (t < 32) {
        const float* pr = &lps[t * 8];
        uint4 pk;
        pk.x = pack2bf(pr[0], pr[1]); pk.y = pack2bf(pr[2], pr[3]);
        pk.z = pack2bf(pr[4], pr[5]); pk.w = pack2bf(pr[6], pr[7]);
        ((uint4*)phi_ws)[(size_t)b * NM + ph * 32 + t] = pk;
    }
}

// ---------------------------------------------------------------------------
// Kernel 2: theta + flash attention, S and PV on mfma_f32_16x16x32_bf16.
// grid NB*32 = 512 blocks, 256 thr = 4 waves; wave = 32 q (2 q-tiles) x 1024 k.
// Round-10: theta computed in-block from the x-tile (block-local data);
// fused PV: B slots j0-3 = kt0 evals, j4-7 = kt1 evals matching g2 .xy/.zw
// -> 12 mfma/kg (was 20), at the 32q/wave traffic point (g2 read once/wave).
// ---------------------------------------------------------------------------
#define KG_STEP(CPP0, CPP1, CG)                                                          \
    {                                                                                    \
        _Pragma("unroll")                                                                \
        for (int qt = 0; qt < 2; ++qt) {                                                 \
            floatx4 s0 = __builtin_amdgcn_mfma_f32_16x16x32_bf16(                        \
                u4s8(CPP0), u4s8(tb[qt]), (floatx4)0.f, 0, 0, 0);                        \
            floatx4 s1 = __builtin_amdgcn_mfma_f32_16x16x32_bf16(                        \
                u4s8(CPP1), u4s8(tb[qt]), (floatx4)0.f, 0, 0, 0);                        \
            float e0[4], e1[4];                                                          \
            _Pragma("unroll")                                                            \
            for (int r = 0; r < 4; ++r) {                                                \
                e0[r] = __builtin_amdgcn_exp2f(s0[r]);                                   \
                e1[r] = __builtin_amdgcn_exp2f(s1[r]);                                   \
            }                                                                            \
            lsum[qt] += ((e0[0] + e0[1]) + (e0[2] + e0[3]))                              \
                      + ((e1[0] + e1[1]) + (e1[2] + e1[3]));                             \
            uint4 pb = make_uint4(pk2fast(e0[0], e0[1]), pk2fast(e0[2], e0[3]),          \
                                  pk2fast(e1[0], e1[1]), pk2fast(e1[2], e1[3]));         \
            _Pragma("unroll")                                                            \
            for (int ct = 0; ct < 4; ++ct)                                               \
                acc[qt][ct] = __builtin_amdgcn_mfma_f32_16x16x32_bf16(                   \
                    u4s8(CG[ct]), u4s8(pb), acc[qt][ct], 0, 0, 0);                       \
        }                                                                                \
    }

__global__ __launch_bounds__(256, 2)
void attn_kernel(const unsigned* __restrict__ phi_ws,
                 const unsigned* __restrict__ g2_ws,
                 const float* __restrict__ w_theta,
                 const float* __restrict__ gamma_p,
                 const float* __restrict__ x,
                 float* __restrict__ out)
{
    // float layout: [lphi 4096][lwt 512][lth 1024][lx 64*132=8448] = 56.3 KB
    // ltr (epilogue transpose, 64*140=8960 floats) aliases lth+lx.
    __shared__ __align__(16) float smem[14080];
    uint4* lphi = (uint4*)smem;          // 1024 uint4, 16 KB
    float* lwt  = smem + 4096;           // theta W [oc][c]
    float* lth  = smem + 4608;           // theta [q 128][oc 8] fp32
    float* lx   = smem + 5632;           // x-tile [c][132]
    float* ltr  = smem + 4608;           // epilogue alias

    const int b    = blockIdx.x >> 5;
    const int qblk = blockIdx.x & 31;
    const int t    = threadIdx.x;
    const int w    = t >> 6;
    const int lane = t & 63;
    const int lm   = lane & 15;
    const int quad = lane >> 4;
    const int q0   = qblk * 128 + w * 32;

    // g2 prefetch (no LDS dependency)
    const uint4* gf = (const uint4*)g2_ws;
    uint4 gA[4], gB[4];
    #pragma unroll
    for (int ct = 0; ct < 4; ++ct) {
        gA[ct] = gf[(((size_t)b * 4 + ct) * 32 + 0) * 64 + lane];
        gB[ct] = gf[(((size_t)b * 4 + ct) * 32 + 1) * 64 + lane];
    }

    // stage phi frags, theta weights, x-tile
    for (int kk = t; kk < NM; kk += 256)
        lphi[kk] = ((const uint4*)phi_ws)[(size_t)b * NM + kk];
    for (int i = t; i < 512; i += 256) lwt[i] = w_theta[i];
    {
        const float* xb = x + (size_t)b * NC * NN + (size_t)qblk * 128;
        for (int idx = t; idx < 2048; idx += 256) {
            int c = idx >> 5, i4 = idx & 31;
            ((float4*)(lx + c * 132))[i4] = ((const float4*)(xb + (size_t)c * NN))[i4];
        }
    }
    __syncthreads();

    // theta: thread covers q-index qi (all 128) x 4 oc -> lth[qi][oc]
    {
        int qi = t & 127, och = (t >> 7) * 4;
        float th4[4] = {0.f, 0.f, 0.f, 0.f};
        for (int c = 0; c < 64; ++c) {
            float xv = lx[c * 132 + qi];             // conflict-free
            #pragma unroll
            for (int o = 0; o < 4; ++o)
                th4[o] = fmaf(lwt[(och + o) * 64 + c], xv, th4[o]);  // broadcast
        }
        *(float4*)&lth[qi * 8 + och] = make_float4(th4[0], th4[1], th4[2], th4[3]);
    }
    __syncthreads();

    // theta B-frags: quad0 holds theta[q][d0..7]*log2e packed bf16, rest zero
    uint4 tb[2];
    #pragma unroll
    for (int qt = 0; qt < 2; ++qt) {
        const float* thp = &lth[(w * 32 + qt * 16 + lm) * 8];
        float4 a = ((const float4*)thp)[0], c4 = ((const float4*)thp)[1];
        uint4 v;
        v.x = pack2bf(a.x * LOG2E, a.y * LOG2E);
        v.y = pack2bf(a.z * LOG2E, a.w * LOG2E);
        v.z = pack2bf(c4.x * LOG2E, c4.y * LOG2E);
        v.w = pack2bf(c4.z * LOG2E, c4.w * LOG2E);
        tb[qt].x = quad == 0 ? v.x : 0u;
        tb[qt].y = quad == 0 ? v.y : 0u;
        tb[qt].z = quad == 0 ? v.z : 0u;
        tb[qt].w = quad == 0 ? v.w : 0u;
    }

    floatx4 acc[2][4];
    #pragma unroll
    for (int qt = 0; qt < 2; ++qt)
        #pragma unroll
        for (int ct = 0; ct < 4; ++ct) acc[qt][ct] = (floatx4)0.f;
    float lsum[2] = {0.f, 0.f};

    uint4 qA0 = lphi[lm],      qA1 = lphi[16 + lm];
    uint4 qB0 = lphi[32 + lm], qB1 = lphi[48 + lm];

    for (int kg2 = 0; kg2 < 16; ++kg2) {
        {   // even kg (buffer A), prefetch kg+2
            uint4 c0 = qA0, c1 = qA1;
            uint4 cg[4] = {gA[0], gA[1], gA[2], gA[3]};
            if (kg2 < 15) {
                int nk = 2 * kg2 + 2;
                qA0 = lphi[nk * 32 + lm];
                qA1 = lphi[nk * 32 + 16 + lm];
                #pragma unroll
                for (int ct = 0; ct < 4; ++ct)
                    gA[ct] = gf[(((size_t)b * 4 + ct) * 32 + nk) * 64 + lane];
            }
            KG_STEP(c0, c1, cg);
        }
        {   // odd kg (buffer B), prefetch kg+2
            uint4 c0 = qB0, c1 = qB1;
            uint4 cg[4] = {gB[0], gB[1], gB[2], gB[3]};
            if (kg2 < 15) {
                int nk = 2 * kg2 + 3;
                qB0 = lphi[nk * 32 + lm];
                qB1 = lphi[nk * 32 + 16 + lm];
                #pragma unroll
                for (int ct = 0; ct < 4; ++ct)
                    gB[ct] = gf[(((size_t)b * 4 + ct) * 32 + nk) * 64 + lane];
            }
            KG_STEP(c0, c1, cg);
        }
    }

    // softmax denominators: quads partition the 32 keys/kg at q=lm
    float inv[2];
    {
        float l0 = lsum[0]; l0 += __shfl_xor(l0, 16); l0 += __shfl_xor(l0, 32);
        float l1 = lsum[1]; l1 += __shfl_xor(l1, 16); l1 += __shfl_xor(l1, 32);
        inv[0] = 1.0f / l0; inv[1] = 1.0f / l1;
    }

    const float gamma = gamma_p[0];

    // transpose epilogue: normalized acc -> ltr[co][q'], then coalesced I/O
    __syncthreads();   // all waves done with lphi/lth/lx
    #pragma unroll
    for (int qt = 0; qt < 2; ++qt)
        #pragma unroll
        for (int ct = 0; ct < 4; ++ct)
            #pragma unroll
            for (int r = 0; r < 4; ++r)
                ltr[(ct * 16 + quad * 4 + r) * 140 + w * 32 + qt * 16 + lm]
                    = acc[qt][ct][r] * inv[qt];
    __syncthreads();

    // thread: 16-lane group covers one co row of 128 q (512 B contiguous)
    {
        const int l16 = t & 15;
        #pragma unroll
        for (int io = 0; io < 4; ++io) {
            int co = io * 16 + (t >> 4);
            size_t base = ((size_t)b * NC + co) * NN + qblk * 128 + l16 * 8;
            const float* tr = &ltr[co * 140 + l16 * 8];
            float4 t0 = ((const float4*)tr)[0];
            float4 t1 = ((const float4*)tr)[1];
            float4 x0 = *(const float4*)(x + base);
            float4 x1 = *(const float4*)(x + base + 4);
            float4 o0 = make_float4(fmaf(gamma, t0.x, x0.x), fmaf(gamma, t0.y, x0.y),
                                    fmaf(gamma, t0.z, x0.z), fmaf(gamma, t0.w, x0.w));
            float4 o1 = make_float4(fmaf(gamma, t1.x, x1.x), fmaf(gamma, t1.y, x1.y),
                                    fmaf(gamma, t1.z, x1.z), fmaf(gamma, t1.w, x1.w));
            *(float4*)(out + base)     = o0;
            *(float4*)(out + base + 4) = o1;
        }
    }
}

// ---------------------------------------------------------------------------
extern "C" void kernel_launch(void* const* d_in, const int* in_sizes, int n_in,
                              void* d_out, int out_size, void* d_ws, size_t ws_size,
                              hipStream_t stream)
{
    const float* x  = (const float*)d_in[0];
    const float* wt = (const float*)d_in[1];
    const float* wp = (const float*)d_in[2];
    const float* wg = (const float*)d_in[3];
    const float* wo = (const float*)d_in[4];
    const float* gm = (const float*)d_in[5];
    float* out = (float*)d_out;

    // ws (bf16, packed): phi 256 KB | g2 (frag order) 2 MB
    unsigned* phi_ws = (unsigned*)d_ws;
    unsigned* g2_ws  = phi_ws + (size_t)NB * NM * ND / 2;

    proj_kernel<<<NB * 32, 256, 0, stream>>>(x, wp, wg, wo, phi_ws, g2_ws);
    attn_kernel<<<NB * 32, 256, 0, stream>>>(phi_ws, g2_ws, wt, gm, x, out);
}